// Round 1
// baseline (216.855 us; speedup 1.0000x reference)
//
#include <hip/hip_runtime.h>

// LinearConv2D fused kernel, fp32.
// Shapes: x[8,128,32,1024], weight[128,16,32,16] -> out[8,128,17,257]
// Decomposition: for each (b,g,fo): y[n,t] = sum_{f in {2fo-1,2fo} valid} sum_{d,w}
//   x[b, g*16+d, f, 4t+w-8] * wt[g*16+n, d, f, w], then leaky_relu(0.01).
//
// Block = (b,g,fo): 320 threads. tn = tid&3 (n-group, n = tn+4j), tg = tid>>2
// (t-group, t = 4*tg+i, tg<=64 valid). Per-thread 4n x 4t register tile.
// Weights (1-2 f slices) staged in LDS with n-stride 260 floats (bank spread).
// x streamed per (f,d): 263 float4 chunks (incl. zero pads), double-buffered,
// row-padded layout (row=8 chunks, 144B stride) to kill the 64B-stride
// bank conflicts on windowed reads.

#define TPB 320

__global__ __launch_bounds__(TPB) void lconv_fused(
    const float* __restrict__ x,   // [8,128,32,1024]
    const float* __restrict__ wt,  // [128,16,32,16]
    float* __restrict__ out)       // [8,128,17,257]
{
    __shared__ float lds[10696];           // 42784 B
    float* wlds = lds;                     // 2 * 16 * 260 = 8320 floats
    float* xlds = lds + 8320;              // 2 * 1188 floats

    const int fo = blockIdx.x;             // 0..16
    const int g  = blockIdx.y;             // 0..7
    const int b  = blockIdx.z;             // 0..7
    const int tid = threadIdx.x;
    const int tn = tid & 3;
    const int tg = tid >> 2;

    // valid f slices feeding this fo (box-sum partitions f into pairs)
    int fvals[2];
    int nf = 0;
    if (2*fo - 1 >= 0) fvals[nf++] = 2*fo - 1;
    if (2*fo < 32)     fvals[nf++] = 2*fo;

    // ---- stage weights: [f2][n][d][w] with n-stride 260 floats ----
    const int witems = nf * 1024;          // float4 items: f2*16n*16d*4(w4)
    for (int idx = tid; idx < witems; idx += TPB) {
        const int f2  = idx >> 10;
        const int rem = idx & 1023;
        const int n   = rem >> 6;
        const int d   = (rem >> 2) & 15;
        const int w4  = idx & 3;
        const float4 v = *(const float4*)(wt + (size_t)(g*16 + n)*8192
                                             + d*512 + fvals[f2]*16 + w4*4);
        *(float4*)(wlds + f2*4160 + n*260 + d*16 + w4*4) = v;
    }

    float acc[4][4];
    #pragma unroll
    for (int j = 0; j < 4; ++j)
        #pragma unroll
        for (int i = 0; i < 4; ++i) acc[j][i] = 0.f;

    const int niter = nf * 16;             // (f2, d) iterations

    // stage x slice for iteration q into buffer bi.
    // chunk c (float4) covers padded time p = 4c..4c+3; global time = p-8.
    // valid global float4 index gi = c-2 in [0,256). Row-padded LDS layout:
    // float offset = (c>>3)*36 + (c&7)*4.
    auto stage = [&](int q, int bi) {
        if (tid < 263) {
            const int f = fvals[q >> 4];
            const int d = q & 15;
            const int c = tid;
            float4 v = make_float4(0.f, 0.f, 0.f, 0.f);
            const int gi = c - 2;
            if (gi >= 0 && gi < 256) {
                v = *(const float4*)(x + (size_t)((b*128 + g*16 + d)*32 + f)*1024
                                       + gi*4);
            }
            *(float4*)(xlds + bi*1188 + ((c >> 3)*36 + (c & 7)*4)) = v;
        }
    };

    stage(0, 0);
    __syncthreads();

    for (int q = 0; q < niter; ++q) {
        const int qb = q & 1;
        if (q + 1 < niter) stage(q + 1, qb ^ 1);

        if (tg <= 64) {
            const int f2 = q >> 4;
            const int d  = q & 15;
            const float* wp = wlds + f2*4160 + tn*260 + d*16;
            const float* xp = xlds + qb*1188;

            // 7 overlapping x chunks cover all (i + w4) in [0,6]
            float4 xv[7];
            const int c0 = tg * 4;
            #pragma unroll
            for (int k = 0; k < 7; ++k) {
                const int c = c0 + k;
                xv[k] = *(const float4*)(xp + ((c >> 3)*36 + (c & 7)*4));
            }
            #pragma unroll
            for (int j = 0; j < 4; ++j) {
                const float* wpj = wp + j*(4*260);
                #pragma unroll
                for (int w4 = 0; w4 < 4; ++w4) {
                    const float4 wv = *(const float4*)(wpj + w4*4);
                    #pragma unroll
                    for (int i = 0; i < 4; ++i) {
                        const float4 xq = xv[i + w4];
                        acc[j][i] = fmaf(wv.x, xq.x, acc[j][i]);
                        acc[j][i] = fmaf(wv.y, xq.y, acc[j][i]);
                        acc[j][i] = fmaf(wv.z, xq.z, acc[j][i]);
                        acc[j][i] = fmaf(wv.w, xq.w, acc[j][i]);
                    }
                }
            }
        }
        __syncthreads();
    }

    // ---- epilogue: leaky_relu + store out[b, g*16+n, fo, t] ----
    if (tg <= 64) {
        const size_t obase = ((size_t)b*128 + g*16)*4369 + (size_t)fo*257;
        #pragma unroll
        for (int j = 0; j < 4; ++j) {
            const int n = tn + 4*j;
            #pragma unroll
            for (int i = 0; i < 4; ++i) {
                const int t = 4*tg + i;
                if (t < 257) {
                    float v = acc[j][i];
                    v = (v > 0.f) ? v : 0.01f*v;
                    out[obase + (size_t)n*4369 + t] = v;
                }
            }
        }
    }
}

extern "C" void kernel_launch(void* const* d_in, const int* in_sizes, int n_in,
                              void* d_out, int out_size, void* d_ws, size_t ws_size,
                              hipStream_t stream) {
    const float* x  = (const float*)d_in[0];
    const float* wt = (const float*)d_in[1];
    float* out      = (float*)d_out;
    dim3 grid(17, 8, 8);   // (fo, g, b)
    lconv_fused<<<grid, TPB, 0, stream>>>(x, wt, out);
}

// Round 2
// 190.186 us; speedup vs baseline: 1.1402x; 1.1402x over previous
//
#include <hip/hip_runtime.h>

// LinearConv2D fused, fp32, producer/consumer wave split.
// x[8,128,32,1024], weight[128,16,32,16] -> out[8,128,17,257]
// Block = (b,g,fo), 320 threads: waves 0-3 = consumers (t 0..255),
// wave 4 = producer (stages x, computes t=256 column).
// y[n,t] = sum_{f in {2fo-1,2fo}} sum_{d,w} x[b,g*16+d,f,4t+w-8]*wt[g*16+n,d,f,w]
// then leaky_relu(0.01).
//
// Consumer thread: tn=tid&7, tg=tid>>3; tile 2n x 8t (n=2tn+j, t=8tg+i).
// Per (f,d): 11 x-float4 + 8 w-float4 ds_reads for 256 FMAs.
// x LDS: row-padded chunks (addr=(c>>3)*36+(c&7)*4 words) -> conflict-free.
// w LDS: n-stride 260 words -> 2-way max (free).
// Producer: issue loads(q+1) -> t256 FMAs -> vmcnt -> ds_write -> barrier,
// so HBM latency hides under consumer compute.

#define TPB 320

__global__ __launch_bounds__(TPB) void lconv_fused2(
    const float* __restrict__ x,   // [8,128,32,1024]
    const float* __restrict__ wt,  // [128,16,32,16]
    float* __restrict__ out)       // [8,128,17,257]
{
    __shared__ float wlds[4160];        // [n=16][stride 260]
    __shared__ float xlds[4752];        // 2 bufs x 2 slices x 1188 words

    const int fo = blockIdx.x;          // 0..16
    const int g  = blockIdx.y;          // 0..7
    const int b  = blockIdx.z;          // 0..7
    const int tid = threadIdx.x;

    int fvals[2]; int nf = 0;
    if (2*fo - 1 >= 0) fvals[nf++] = 2*fo - 1;
    if (2*fo < 32)     fvals[nf++] = 2*fo;
    const int niter = nf * 8;           // d-pair iterations

    const bool producer = (tid >= 256);
    const int plane = tid - 256;        // producer lane 0..63

    const size_t xbase_bg = (size_t)(b*128 + g*16) * 32768; // + d*32768 + f*1024 + time

    // ---------- producer staging (regs <-> LDS) ----------
    float4 xr[9];
    auto stage_issue = [&](int q) {
        const int f  = fvals[q >> 3];
        const int d0 = (q & 7) * 2;
        #pragma unroll
        for (int k = 0; k < 9; ++k) {
            const int m = plane + 64*k;
            float4 v = make_float4(0.f, 0.f, 0.f, 0.f);
            if (m < 520) {
                const int s  = (m >= 260) ? 1 : 0;
                const int c  = m - s*260;
                const int gi = c - 2;
                if (gi >= 0 && gi < 256)
                    v = *(const float4*)(x + xbase_bg + (size_t)(d0+s)*32768
                                           + (size_t)f*1024 + gi*4);
            }
            xr[k] = v;
        }
    };
    auto stage_write = [&](int q) {
        float* dst = xlds + (q & 1) * 2376;
        #pragma unroll
        for (int k = 0; k < 9; ++k) {
            const int m = plane + 64*k;
            if (m < 520) {
                const int s = (m >= 260) ? 1 : 0;
                const int c = m - s*260;
                *(float4*)(dst + s*1188 + (c >> 3)*36 + (c & 7)*4) = xr[k];
            }
        }
    };

    // ---------- weight staging: one f-slice [16n][16d][16w] ----------
    auto wload = [&](int f) {
        if (tid < 256) {
            #pragma unroll
            for (int r = 0; r < 4; ++r) {
                const int idx = tid + 256*r;        // n*64 + d*4 + w4
                const int n  = idx >> 6;
                const int dd = (idx >> 2) & 15;
                const int w4 = idx & 3;
                const float4 v = *(const float4*)(wt + (size_t)(g*16 + n)*8192
                                                     + dd*512 + f*16 + w4*4);
                *(float4*)(wlds + n*260 + dd*16 + w4*4) = v;
            }
        }
    };

    // ---------- prologue ----------
    if (producer) stage_issue(0);
    wload(fvals[0]);
    if (producer) stage_write(0);
    __syncthreads();

    float acc[2][8];
    #pragma unroll
    for (int j = 0; j < 2; ++j)
        #pragma unroll
        for (int i = 0; i < 8; ++i) acc[j][i] = 0.f;
    float a256 = 0.f;

    const int tn = tid & 7;
    const int tg = tid >> 3;

    for (int q = 0; q < niter; ++q) {
        if (q == 8) {                    // f-slice boundary (only when nf==2)
            wload(fvals[1]);
            __syncthreads();
        }

        if (producer) {
            if (q + 1 < niter) stage_issue(q + 1);
            // t = 256 column: lanes 0..15, n = plane
            if (plane < 16) {
                const float* xb = xlds + (q & 1) * 2376;
                const int dbase = (q & 7) * 2;
                #pragma unroll
                for (int s = 0; s < 2; ++s) {
                    const float* xs = xb + s*1188;      // chunks 256..259 @ words 1152..1167
                    const float* wp = wlds + plane*260 + (dbase + s)*16;
                    #pragma unroll
                    for (int w4 = 0; w4 < 4; ++w4) {
                        const float4 wv = *(const float4*)(wp + w4*4);
                        const float4 xq = *(const float4*)(xs + 1152 + w4*4);
                        a256 = fmaf(wv.x, xq.x, a256);
                        a256 = fmaf(wv.y, xq.y, a256);
                        a256 = fmaf(wv.z, xq.z, a256);
                        a256 = fmaf(wv.w, xq.w, a256);
                    }
                }
            }
            if (q + 1 < niter) stage_write(q + 1);
        } else {
            const float* xb = xlds + (q & 1) * 2376;
            const int dbase = (q & 7) * 2;
            #pragma unroll
            for (int s = 0; s < 2; ++s) {
                const float* xs = xb + s*1188;
                float4 xv[11];
                const int c0 = tg * 8;
                #pragma unroll
                for (int k = 0; k < 11; ++k) {
                    const int c = c0 + k;
                    xv[k] = *(const float4*)(xs + (c >> 3)*36 + (c & 7)*4);
                }
                #pragma unroll
                for (int j = 0; j < 2; ++j) {
                    const float* wp = wlds + (tn*2 + j)*260 + (dbase + s)*16;
                    #pragma unroll
                    for (int w4 = 0; w4 < 4; ++w4) {
                        const float4 wv = *(const float4*)(wp + w4*4);
                        #pragma unroll
                        for (int i = 0; i < 8; ++i) {
                            const float4 xq = xv[i + w4];
                            acc[j][i] = fmaf(wv.x, xq.x, acc[j][i]);
                            acc[j][i] = fmaf(wv.y, xq.y, acc[j][i]);
                            acc[j][i] = fmaf(wv.z, xq.z, acc[j][i]);
                            acc[j][i] = fmaf(wv.w, xq.w, acc[j][i]);
                        }
                    }
                }
            }
        }
        __syncthreads();
    }

    // ---------- epilogue ----------
    if (producer) {
        if (plane < 16) {
            float v = a256;
            v = (v > 0.f) ? v : 0.01f*v;
            out[((size_t)(b*128 + g*16 + plane)*17 + fo)*257 + 256] = v;
        }
    } else {
        #pragma unroll
        for (int j = 0; j < 2; ++j) {
            const size_t rbase = ((size_t)(b*128 + g*16 + tn*2 + j)*17 + fo)*257;
            #pragma unroll
            for (int i = 0; i < 8; ++i) {
                float v = acc[j][i];
                v = (v > 0.f) ? v : 0.01f*v;
                out[rbase + tg*8 + i] = v;
            }
        }
    }
}

extern "C" void kernel_launch(void* const* d_in, const int* in_sizes, int n_in,
                              void* d_out, int out_size, void* d_ws, size_t ws_size,
                              hipStream_t stream) {
    const float* x  = (const float*)d_in[0];
    const float* wt = (const float*)d_in[1];
    float* out      = (float*)d_out;
    dim3 grid(17, 8, 8);   // (fo, g, b)
    lconv_fused2<<<grid, TPB, 0, stream>>>(x, wt, out);
}

// Round 3
// 84.154 us; speedup vs baseline: 2.5769x; 2.2600x over previous
//
#include <hip/hip_runtime.h>

// LinearConv2D fused, fp32, v3.
// x[8,128,32,1024], weight[128,16,32,16] -> out[8,128,17,257]
// y[n,t] = sum_{f in {2fo-1,2fo}} sum_{d,w} x[b,g*16+d,f,4t+w-8]*wt[g*16+n,d,f,w]
// Block = (b,g,fo), 256 threads = 4 waves. Wave w owns n = 4w..4w+3 ->
// weight loads are wave-uniform => scalar (SMEM) loads, no LDS for weights.
// Lane l owns t = 4l..4l+3. x staged per (f,d) slice via global_load_lds
// (async, drained by the post-compute barrier) into a double-buffered,
// source-swizzled LDS layout: slot s holds chunk c = 2 + (s ^ ((s>>3)&7))
// (involution; applied on both the global source address and the read
// address) so the stride-16B windowed b128 reads spread across bank groups.
// t=256 (half-window edge column) is computed in a tiny direct-global
// epilogue instead of widening the main loop.

#define TPB 256

__global__ __launch_bounds__(TPB, 4) void lconv3(
    const float* __restrict__ x,   // [8,128,32,1024]
    const float* __restrict__ wt,  // [128,16,32,16]
    float* __restrict__ out)       // [8,128,17,257]
{
    __shared__ float4 xbuf[2][256];    // 8 KB: 2 bufs x 256 slots
    __shared__ float4 zero4;           // stays zero (left/right pad chunks)
    __shared__ float red[4][16];       // t=256 cross-wave reduction

    const int fo  = blockIdx.x;        // 0..16
    const int g   = blockIdx.y;        // 0..7
    const int b   = blockIdx.z;        // 0..7
    const int tid = threadIdx.x;
    const int lane = tid & 63;
    const int wid_v = tid >> 6;
    const int wid = __builtin_amdgcn_readfirstlane(wid_v);
    const int n0 = wid * 4;

    int fvals[2]; int nf = 0;
    if (2*fo - 1 >= 0) fvals[nf++] = 2*fo - 1;
    if (2*fo < 32)     fvals[nf++] = 2*fo;
    const int niter = nf * 16;

    if (tid == 0) zero4 = make_float4(0.f, 0.f, 0.f, 0.f);

    // staging: thread's LDS slot = tid; it holds global chunk e+2, e = swz(tid)
    const int e_stage = tid ^ ((tid >> 3) & 7);
    const size_t xrow_bg = (size_t)(b*128 + g*16) * 32768;  // + d*32768 + f*1024

    auto stage = [&](int q, int bi) {
        const int f = fvals[q >> 4];
        const int d = q & 15;
        const float* src = x + xrow_bg + (size_t)d*32768 + (size_t)f*1024
                             + (size_t)e_stage*4;
        __builtin_amdgcn_global_load_lds(
            (const __attribute__((address_space(1))) void*)src,
            (__attribute__((address_space(3))) void*)&xbuf[bi][tid],
            16, 0, 0);
    };

    // read offsets: lane l needs chunks c = 4l..4l+6 (c valid in [2,257])
    int slotk[7];
    #pragma unroll
    for (int k = 0; k < 7; ++k) {
        const int e = 4*lane + k - 2;
        slotk[k] = (e >= 0 && e < 256) ? (e ^ ((e >> 3) & 7)) : -1;
    }

    float acc[4][4];
    #pragma unroll
    for (int j = 0; j < 4; ++j)
        #pragma unroll
        for (int i = 0; i < 4; ++i) acc[j][i] = 0.f;

    stage(0, 0);
    __syncthreads();   // drains stage(0); also publishes zero4

    for (int q = 0; q < niter; ++q) {
        const int bi = q & 1;
        if (q + 1 < niter) stage(q + 1, bi ^ 1);

        const int f = fvals[q >> 4];
        const int d = q & 15;

        // wave-uniform scalar weight loads: 4 n-rows x 16 w
        const int woff = __builtin_amdgcn_readfirstlane(
            (g*16 + n0)*8192 + d*512 + f*16);
        const float* wb = wt + woff;
        float4 wv[4][4];
        #pragma unroll
        for (int j = 0; j < 4; ++j)
            #pragma unroll
            for (int w4 = 0; w4 < 4; ++w4)
                wv[j][w4] = *(const float4*)(wb + j*8192 + w4*4);

        // x fragment: 7 overlapping chunks
        float4 xv[7];
        #pragma unroll
        for (int k = 0; k < 7; ++k) {
            const int s = slotk[k];
            const float4* p = (s >= 0) ? (&xbuf[bi][0] + s) : &zero4;
            xv[k] = *p;
        }

        #pragma unroll
        for (int j = 0; j < 4; ++j)
            #pragma unroll
            for (int w4 = 0; w4 < 4; ++w4) {
                const float4 wq = wv[j][w4];
                #pragma unroll
                for (int i = 0; i < 4; ++i) {
                    const float4 xq = xv[i + w4];
                    acc[j][i] = fmaf(wq.x, xq.x, acc[j][i]);
                    acc[j][i] = fmaf(wq.y, xq.y, acc[j][i]);
                    acc[j][i] = fmaf(wq.z, xq.z, acc[j][i]);
                    acc[j][i] = fmaf(wq.w, xq.w, acc[j][i]);
                }
            }

        __syncthreads();  // drains stage(q+1) + protects buffer rotation
    }

    // ---- epilogue: t = 0..255 ----
    {
        const size_t obase = (size_t)(b*128 + g*16 + n0) * 4369
                           + (size_t)fo * 257 + 4*lane;
        #pragma unroll
        for (int j = 0; j < 4; ++j) {
            #pragma unroll
            for (int i = 0; i < 4; ++i) {
                float v = acc[j][i];
                v = (v > 0.f) ? v : 0.01f*v;
                out[obase + (size_t)j*4369 + i] = v;
            }
        }
    }

    // ---- epilogue: t = 256 (window uses only w=0..7; rest is pad) ----
    {
        const int n = tid & 15;
        const int d = tid >> 4;
        float p = 0.f;
        for (int s = 0; s < nf; ++s) {
            const int f = fvals[s];
            const float* xr = x + xrow_bg + (size_t)d*32768 + (size_t)f*1024 + 1016;
            const float* wr = wt + (size_t)(g*16 + n)*8192 + (size_t)d*512 + f*16;
            #pragma unroll
            for (int w = 0; w < 8; ++w) p = fmaf(xr[w], wr[w], p);
        }
        // sum over d: lanes l, l^16, l^32 within wave hold d = 4w + (l>>4)
        p += __shfl_xor(p, 16);
        p += __shfl_xor(p, 32);
        if (lane < 16) red[wid_v][lane] = p;   // partial for n=lane, 4 d's
        __syncthreads();
        if (tid < 16) {
            float v = red[0][tid] + red[1][tid] + red[2][tid] + red[3][tid];
            v = (v > 0.f) ? v : 0.01f*v;
            out[(size_t)(b*128 + g*16 + tid) * 4369 + (size_t)fo * 257 + 256] = v;
        }
    }
}

extern "C" void kernel_launch(void* const* d_in, const int* in_sizes, int n_in,
                              void* d_out, int out_size, void* d_ws, size_t ws_size,
                              hipStream_t stream) {
    const float* x  = (const float*)d_in[0];
    const float* wt = (const float*)d_in[1];
    float* out      = (float*)d_out;
    dim3 grid(17, 8, 8);   // (fo, g, b)
    lconv3<<<grid, TPB, 0, stream>>>(x, wt, out);
}